// Round 2
// baseline (2691.996 us; speedup 1.0000x reference)
//
#include <hip/hip_runtime.h>
#include <math.h>

#define NN 4096
#define EE 65536
#define HID_ 128
#define NH_HEADS 4
#define HDIM 32
#define NCOL 4097

static constexpr float SCALE_ATT = 0.17677669529663687f;   // 1/sqrt(32)
static constexpr float INV_SQRT_D = 0.08838834764831845f;  // 1/sqrt(128)

__device__ __forceinline__ float wred64(float v) {
#pragma unroll
  for (int m = 32; m > 0; m >>= 1) v += __shfl_xor(v, m, 64);
  return v;
}

// ---------------- generic [4096,128] @ [128,128] GEMM, pair-batched -----------
template <bool BIAS, bool RELU, bool RESID>
__global__ __launch_bounds__(256, 2) void gemm128_k(
    const float* __restrict__ x0, const float* __restrict__ x1,
    const float* __restrict__ w, const float* __restrict__ bias,
    const float* __restrict__ res0, const float* __restrict__ res1,
    float* __restrict__ o0, float* __restrict__ o1) {
  const float* x = blockIdx.y ? x1 : x0;
  const float* res = blockIdx.y ? res1 : res0;
  float* out = blockIdx.y ? o1 : o0;
  __shared__ float Xs[32][132];
  __shared__ float Ws[32][128];
  const int tid = threadIdx.x;
  const int rowbase = blockIdx.x * 32;
#pragma unroll
  for (int i = 0; i < 4; ++i) {
    int lin = tid + i * 256;
    int r = lin >> 5, c4 = lin & 31;
    *(float4*)&Xs[r][c4 * 4] =
        *(const float4*)&x[(size_t)(rowbase + r) * HID_ + c4 * 4];
  }
  float acc[4][4] = {};
  const int tr = tid >> 5, tc = tid & 31;
  const int r0 = tr * 4, c0 = tc * 4;
  for (int k0 = 0; k0 < 128; k0 += 32) {
    __syncthreads();
#pragma unroll
    for (int i = 0; i < 4; ++i) {
      int lin = tid + i * 256;
      int r = lin >> 5, c4 = lin & 31;
      *(float4*)&Ws[r][c4 * 4] =
          *(const float4*)&w[(size_t)(k0 + r) * HID_ + c4 * 4];
    }
    __syncthreads();
#pragma unroll
    for (int kk = 0; kk < 32; kk += 4) {
      float4 wv0 = *(const float4*)&Ws[kk + 0][c0];
      float4 wv1 = *(const float4*)&Ws[kk + 1][c0];
      float4 wv2 = *(const float4*)&Ws[kk + 2][c0];
      float4 wv3 = *(const float4*)&Ws[kk + 3][c0];
#pragma unroll
      for (int r = 0; r < 4; ++r) {
        // FIX (round 1): index X at k0+kk, not kk — the X panel spans all 128
        // K-columns but the previous code re-read columns 0..31 for every k0.
        float4 xv = *(const float4*)&Xs[r0 + r][k0 + kk];
        acc[r][0] += xv.x * wv0.x + xv.y * wv1.x + xv.z * wv2.x + xv.w * wv3.x;
        acc[r][1] += xv.x * wv0.y + xv.y * wv1.y + xv.z * wv2.y + xv.w * wv3.y;
        acc[r][2] += xv.x * wv0.z + xv.y * wv1.z + xv.z * wv2.z + xv.w * wv3.z;
        acc[r][3] += xv.x * wv0.w + xv.y * wv1.w + xv.z * wv2.w + xv.w * wv3.w;
      }
    }
  }
  float4 bv = make_float4(0.f, 0.f, 0.f, 0.f);
  if (BIAS) bv = *(const float4*)&bias[c0];
#pragma unroll
  for (int r = 0; r < 4; ++r) {
    size_t orow = (size_t)(rowbase + r0 + r) * HID_ + c0;
    float4 ov;
    ov.x = acc[r][0] + bv.x;
    ov.y = acc[r][1] + bv.y;
    ov.z = acc[r][2] + bv.z;
    ov.w = acc[r][3] + bv.w;
    if (RESID) {
      float4 rv = *(const float4*)&res[orow];
      ov.x += rv.x; ov.y += rv.y; ov.z += rv.z; ov.w += rv.w;
    }
    if (RELU) {
      ov.x = fmaxf(ov.x, 0.f); ov.y = fmaxf(ov.y, 0.f);
      ov.z = fmaxf(ov.z, 0.f); ov.w = fmaxf(ov.w, 0.f);
    }
    *(float4*)&out[orow] = ov;
  }
}

// ---------------- GCN graph build ------------------------------------------
__global__ void count_deg_k(const int* __restrict__ eiA,
                            const int* __restrict__ eiB, int* cntA, int* cntB) {
  int e = blockIdx.x * 256 + threadIdx.x;
  const int* ei = blockIdx.y ? eiB : eiA;
  int* cnt = blockIdx.y ? cntB : cntA;
  atomicAdd(&cnt[ei[EE + e]], 1);
}

__global__ __launch_bounds__(1024) void scan_k(const int* cntA, const int* cntB,
                                               int* rpA, int* rpB, float* dinvA,
                                               float* dinvB) {
  const int* cnt = blockIdx.y ? cntB : cntA;
  int* rp = blockIdx.y ? rpB : rpA;
  float* dinv = blockIdx.y ? dinvB : dinvA;
  __shared__ int part[1024];
  int tid = threadIdx.x;
  int v0 = cnt[tid * 4], v1 = cnt[tid * 4 + 1], v2 = cnt[tid * 4 + 2],
      v3 = cnt[tid * 4 + 3];
  int tot = v0 + v1 + v2 + v3;
  part[tid] = tot;
  __syncthreads();
  int x = tot;
  for (int off = 1; off < 1024; off <<= 1) {
    int y = (tid >= off) ? part[tid - off] : 0;
    __syncthreads();
    x += y;
    part[tid] = x;
    __syncthreads();
  }
  int excl = x - tot;
  rp[tid * 4] = excl;
  rp[tid * 4 + 1] = excl + v0;
  rp[tid * 4 + 2] = excl + v0 + v1;
  rp[tid * 4 + 3] = excl + v0 + v1 + v2;
  if (tid == 1023) rp[4096] = x;
  dinv[tid * 4] = rsqrtf((float)(v0 + 1));
  dinv[tid * 4 + 1] = rsqrtf((float)(v1 + 1));
  dinv[tid * 4 + 2] = rsqrtf((float)(v2 + 1));
  dinv[tid * 4 + 3] = rsqrtf((float)(v3 + 1));
}

__global__ void fill_k(const int* __restrict__ eiA, const int* __restrict__ eiB,
                       const int* rpA, const int* rpB, int* fillA, int* fillB,
                       int* srcA, int* srcB) {
  int e = blockIdx.x * 256 + threadIdx.x;
  const int* ei = blockIdx.y ? eiB : eiA;
  const int* rp = blockIdx.y ? rpB : rpA;
  int* fill = blockIdx.y ? fillB : fillA;
  int* src = blockIdx.y ? srcB : srcA;
  int d = ei[EE + e], s = ei[e];
  int pos = atomicAdd(&fill[d], 1);
  src[rp[d] + pos] = s;
}

// wave-per-node aggregation + bias + LayerNorm + ReLU
__global__ __launch_bounds__(256) void gcn_agg_k(
    const float* __restrict__ xlA, const float* __restrict__ xlB,
    const int* __restrict__ rpA, const int* __restrict__ rpB,
    const int* __restrict__ srcA, const int* __restrict__ srcB,
    const float* __restrict__ dinvA, const float* __restrict__ dinvB,
    const float* __restrict__ gb, const float* __restrict__ lg,
    const float* __restrict__ lb, float* __restrict__ outA,
    float* __restrict__ outB) {
  const float* xl = blockIdx.y ? xlB : xlA;
  const int* rp = blockIdx.y ? rpB : rpA;
  const int* src = blockIdx.y ? srcB : srcA;
  const float* dinv = blockIdx.y ? dinvB : dinvA;
  float* out = blockIdx.y ? outB : outA;
  int wid = threadIdx.x >> 6, lane = threadIdx.x & 63;
  int node = blockIdx.x * 4 + wid;
  int b = rp[node], e = rp[node + 1];
  float di = dinv[node];
  float a0 = 0.f, a1 = 0.f;
  for (int base = b; base < e; base += 64) {
    int rem = e - base;
    int sv = 0;
    float wv = 0.f;
    if (lane < rem) {
      int s = src[base + lane];
      sv = s;
      wv = dinv[s] * di;
    }
    int nch = rem < 64 ? rem : 64;
    for (int j = 0; j < nch; ++j) {
      int s = __shfl(sv, j, 64);
      float w = __shfl(wv, j, 64);
      a0 += xl[(size_t)s * HID_ + lane] * w;
      a1 += xl[(size_t)s * HID_ + 64 + lane] * w;
    }
  }
  a0 += xl[(size_t)node * HID_ + lane] * di * di;
  a1 += xl[(size_t)node * HID_ + 64 + lane] * di * di;
  a0 += gb[lane];
  a1 += gb[64 + lane];
  float mean = wred64(a0 + a1) * (1.f / 128.f);
  float d0 = a0 - mean, d1 = a1 - mean;
  float var = wred64(d0 * d0 + d1 * d1) * (1.f / 128.f);
  float rs = rsqrtf(var + 1e-5f);
  float o0 = d0 * rs * lg[lane] + lb[lane];
  float o1 = d1 * rs * lg[64 + lane] + lb[64 + lane];
  out[(size_t)node * HID_ + lane] = fmaxf(o0, 0.f);
  out[(size_t)node * HID_ + 64 + lane] = fmaxf(o1, 0.f);
}

// ---------------- LayerNorm in-place (wave per row) -------------------------
__global__ __launch_bounds__(256) void ln_k(float* __restrict__ hA,
                                            float* __restrict__ hB,
                                            const float* __restrict__ g,
                                            const float* __restrict__ b) {
  float* h = blockIdx.y ? hB : hA;
  int wid = threadIdx.x >> 6, lane = threadIdx.x & 63;
  int row = blockIdx.x * 4 + wid;
  float a0 = h[(size_t)row * HID_ + lane];
  float a1 = h[(size_t)row * HID_ + 64 + lane];
  float mean = wred64(a0 + a1) * (1.f / 128.f);
  float d0 = a0 - mean, d1 = a1 - mean;
  float var = wred64(d0 * d0 + d1 * d1) * (1.f / 128.f);
  float rs = rsqrtf(var + 1e-5f);
  h[(size_t)row * HID_ + lane] = d0 * rs * g[lane] + b[lane];
  h[(size_t)row * HID_ + 64 + lane] = d1 * rs * g[64 + lane] + b[64 + lane];
}

// ---------------- attention (fp32, no-max online softmax, k-sliced) ---------
// grid: (8 row-tiles, 4 heads, dir*4+slice), block 256; 2 q-rows/thread.
__global__ __launch_bounds__(256, 1) void attn_k(
    const float* __restrict__ QA, const float* __restrict__ KA,
    const float* __restrict__ VA, const float* __restrict__ QB,
    const float* __restrict__ KB, const float* __restrict__ VB,
    float* __restrict__ Opart, float* __restrict__ lpart) {
  int rt = blockIdx.x, h = blockIdx.y, ds = blockIdx.z;
  int dir = ds >> 2, slice = ds & 3;
  const float* Q = dir ? QB : QA;
  const float* K = dir ? KA : KB;
  const float* V = dir ? VA : VB;
  int tid = threadIdx.x;
  int ra = rt * 512 + tid, rb = ra + 256;
  float q0[32], q1[32];
#pragma unroll
  for (int k4 = 0; k4 < 8; ++k4) {
    float4 a = *(const float4*)&Q[(size_t)ra * HID_ + h * HDIM + k4 * 4];
    float4 c = *(const float4*)&Q[(size_t)rb * HID_ + h * HDIM + k4 * 4];
    q0[k4 * 4 + 0] = a.x * SCALE_ATT; q0[k4 * 4 + 1] = a.y * SCALE_ATT;
    q0[k4 * 4 + 2] = a.z * SCALE_ATT; q0[k4 * 4 + 3] = a.w * SCALE_ATT;
    q1[k4 * 4 + 0] = c.x * SCALE_ATT; q1[k4 * 4 + 1] = c.y * SCALE_ATT;
    q1[k4 * 4 + 2] = c.z * SCALE_ATT; q1[k4 * 4 + 3] = c.w * SCALE_ATT;
  }
  float o0[32] = {}, o1[32] = {};
  float l0 = 0.f, l1 = 0.f;
  __shared__ float Ks[32][36], Vs[32][36];
  int kbase = slice * 1024;
  for (int t = 0; t < 32; ++t) {
    __syncthreads();
#pragma unroll
    for (int it = 0; it < 2; ++it) {
      int l2 = tid + it * 256;
      int row = (l2 >> 3) & 31, c4 = l2 & 7;
      const float* sp = (l2 >> 8) ? V : K;
      float4 v =
          *(const float4*)&sp[(size_t)(kbase + t * 32 + row) * HID_ + h * HDIM + c4 * 4];
      float* dst = (l2 >> 8) ? &Vs[row][c4 * 4] : &Ks[row][c4 * 4];
      *(float4*)dst = v;
    }
    __syncthreads();
    for (int j = 0; j < 32; ++j) {
      float s0 = 0.f, s1 = 0.f;
#pragma unroll
      for (int k4 = 0; k4 < 8; ++k4) {
        float4 kv = *(const float4*)&Ks[j][k4 * 4];
        s0 += q0[k4 * 4 + 0] * kv.x + q0[k4 * 4 + 1] * kv.y +
              q0[k4 * 4 + 2] * kv.z + q0[k4 * 4 + 3] * kv.w;
        s1 += q1[k4 * 4 + 0] * kv.x + q1[k4 * 4 + 1] * kv.y +
              q1[k4 * 4 + 2] * kv.z + q1[k4 * 4 + 3] * kv.w;
      }
      float p0 = __expf(s0), p1 = __expf(s1);
      l0 += p0;
      l1 += p1;
#pragma unroll
      for (int f4 = 0; f4 < 8; ++f4) {
        float4 vv = *(const float4*)&Vs[j][f4 * 4];
        o0[f4 * 4 + 0] += p0 * vv.x; o0[f4 * 4 + 1] += p0 * vv.y;
        o0[f4 * 4 + 2] += p0 * vv.z; o0[f4 * 4 + 3] += p0 * vv.w;
        o1[f4 * 4 + 0] += p1 * vv.x; o1[f4 * 4 + 1] += p1 * vv.y;
        o1[f4 * 4 + 2] += p1 * vv.z; o1[f4 * 4 + 3] += p1 * vv.w;
      }
    }
  }
  size_t pb = (size_t)(slice * 2 + dir);
#pragma unroll
  for (int f4 = 0; f4 < 8; ++f4) {
    *(float4*)&Opart[(pb * NN + ra) * HID_ + h * HDIM + f4 * 4] = make_float4(
        o0[f4 * 4 + 0], o0[f4 * 4 + 1], o0[f4 * 4 + 2], o0[f4 * 4 + 3]);
    *(float4*)&Opart[(pb * NN + rb) * HID_ + h * HDIM + f4 * 4] = make_float4(
        o1[f4 * 4 + 0], o1[f4 * 4 + 1], o1[f4 * 4 + 2], o1[f4 * 4 + 3]);
  }
  lpart[(size_t)(slice * 8 + dir * 4 + h) * NN + ra] = l0;
  lpart[(size_t)(slice * 8 + dir * 4 + h) * NN + rb] = l1;
}

__global__ void attn_combine_k(const float* __restrict__ Opart,
                               const float* __restrict__ lpart,
                               float* __restrict__ outA,
                               float* __restrict__ outB) {
  int row = blockIdx.x, dir = blockIdx.y, f = threadIdx.x;
  int h = f >> 5;
  float o = 0.f, l = 0.f;
#pragma unroll
  for (int s = 0; s < 4; ++s) {
    o += Opart[((size_t)(s * 2 + dir) * NN + row) * HID_ + f];
    l += lpart[(size_t)(s * 8 + dir * 4 + h) * NN + row];
  }
  float* out = dir ? outB : outA;
  out[(size_t)row * HID_ + f] = o / l;
}

// ---------------- logits = (Ap @ Bp^T) * inv_sqrt_d -------------------------
__global__ __launch_bounds__(256, 2) void gemm_nt_k(const float* __restrict__ A,
                                                    const float* __restrict__ B,
                                                    float* __restrict__ L) {
  __shared__ float As[64][132];
  __shared__ float BsT[128][68];
  int tid = threadIdx.x;
  int ab = blockIdx.y * 64, bb = blockIdx.x * 64;
#pragma unroll
  for (int i = 0; i < 8; ++i) {
    int lin = tid + i * 256;
    int r = lin >> 5, c4 = lin & 31;
    *(float4*)&As[r][c4 * 4] =
        *(const float4*)&A[(size_t)(ab + r) * HID_ + c4 * 4];
  }
#pragma unroll
  for (int i = 0; i < 32; ++i) {
    int lin = tid + i * 256;
    int r = lin >> 7, k = lin & 127;
    BsT[k][r] = B[(size_t)(bb + r) * HID_ + k];
  }
  __syncthreads();
  int tr = tid >> 4, tc = tid & 15;
  int r0 = tr * 4, c0 = tc * 4;
  float acc[4][4] = {};
#pragma unroll
  for (int k = 0; k < 128; k += 4) {
    float4 bv0 = *(const float4*)&BsT[k + 0][c0];
    float4 bv1 = *(const float4*)&BsT[k + 1][c0];
    float4 bv2 = *(const float4*)&BsT[k + 2][c0];
    float4 bv3 = *(const float4*)&BsT[k + 3][c0];
#pragma unroll
    for (int r = 0; r < 4; ++r) {
      float4 av = *(const float4*)&As[r0 + r][k];
      acc[r][0] += av.x * bv0.x + av.y * bv1.x + av.z * bv2.x + av.w * bv3.x;
      acc[r][1] += av.x * bv0.y + av.y * bv1.y + av.z * bv2.y + av.w * bv3.y;
      acc[r][2] += av.x * bv0.z + av.y * bv1.z + av.z * bv2.z + av.w * bv3.z;
      acc[r][3] += av.x * bv0.w + av.y * bv1.w + av.z * bv2.w + av.w * bv3.w;
    }
  }
#pragma unroll
  for (int r = 0; r < 4; ++r)
#pragma unroll
    for (int c = 0; c < 4; ++c)
      L[(size_t)(ab + r0 + r) * NCOL + bb + c0 + c] = acc[r][c] * INV_SQRT_D;
}

__global__ void null_col_k(const float* __restrict__ Ap,
                           const float* __restrict__ nv,
                           float* __restrict__ L) {
  int row = blockIdx.x, lane = threadIdx.x;
  float s = Ap[(size_t)row * HID_ + lane] * nv[lane] +
            Ap[(size_t)row * HID_ + 64 + lane] * nv[64 + lane];
  s = wred64(s);
  if (lane == 0) L[(size_t)row * NCOL + 4096] = s * INV_SQRT_D;
}

// ---------------- Sinkhorn via r/c offset vectors ---------------------------
__global__ __launch_bounds__(256) void sink_row_k(const float* __restrict__ L,
                                                  const float* __restrict__ c,
                                                  float* __restrict__ r) {
  int row = blockIdx.x, tid = threadIdx.x;
  const float* Lr = L + (size_t)row * NCOL;
  float s = 0.f;
  for (int j = tid; j < NCOL; j += 256) s += __expf(Lr[j] - c[j]);
  s = wred64(s);
  __shared__ float red[4];
  int wid = tid >> 6, lane = tid & 63;
  if (lane == 0) red[wid] = s;
  __syncthreads();
  if (tid == 0) r[row] = __logf(red[0] + red[1] + red[2] + red[3]);
}

__global__ __launch_bounds__(256) void sink_colp_k(const float* __restrict__ L,
                                                   const float* __restrict__ r,
                                                   float* __restrict__ part) {
  int j = blockIdx.x * 256 + threadIdx.x;
  int rc = blockIdx.y;
  if (j >= NCOL) return;
  float s = 0.f;
  int i0 = rc * 128;
#pragma unroll 4
  for (int i = 0; i < 128; ++i)
    s += __expf(L[(size_t)(i0 + i) * NCOL + j] - r[i0 + i]);
  part[(size_t)rc * NCOL + j] = s;
}

__global__ void sink_colc_k(const float* __restrict__ part,
                            float* __restrict__ c) {
  int j = blockIdx.x * 256 + threadIdx.x;
  if (j >= NCOL) return;
  float s = 0.f;
#pragma unroll
  for (int rc = 0; rc < 32; ++rc) s += part[(size_t)rc * NCOL + j];
  c[j] = __logf(s);
}

__global__ __launch_bounds__(256) void sink_final_k(const float* __restrict__ L,
                                                    const float* __restrict__ r,
                                                    const float* __restrict__ c,
                                                    float* __restrict__ P) {
  int row = blockIdx.x;
  float rv = r[row];
  for (int j = threadIdx.x; j < NCOL; j += 256)
    P[(size_t)row * NCOL + j] = __expf(L[(size_t)row * NCOL + j] - rv - c[j]);
}

// ---------------- host ------------------------------------------------------
extern "C" void kernel_launch(void* const* d_in, const int* in_sizes, int n_in,
                              void* d_out, int out_size, void* d_ws,
                              size_t ws_size, hipStream_t stream) {
  const float* A_x = (const float*)d_in[0];
  const int* A_ei = (const int*)d_in[1];
  const float* B_x = (const float*)d_in[2];
  const int* B_ei = (const int*)d_in[3];
  const float* in_w = (const float*)d_in[4];
  const float* in_b = (const float*)d_in[5];
  const float* gcn_w = (const float*)d_in[6];
  const float* gcn_b = (const float*)d_in[7];
  const float* lng = (const float*)d_in[8];
  const float* lnb = (const float*)d_in[9];
  const float* cq = (const float*)d_in[10];
  const float* ck = (const float*)d_in[11];
  const float* cv = (const float*)d_in[12];
  const float* co = (const float*)d_in[13];
  const float* cob = (const float*)d_in[14];
  const float* plg = (const float*)d_in[15];
  const float* plb = (const float*)d_in[16];
  const float* pw = (const float*)d_in[17];
  const float* pb = (const float*)d_in[18];
  const float* nullv = (const float*)d_in[19];
  const float* w1 = (const float*)d_in[20];
  const float* b1 = (const float*)d_in[21];
  const float* w2 = (const float*)d_in[22];
  const float* b2 = (const float*)d_in[23];

  float* ws = (float*)d_ws;
  size_t off = 0;
  auto alloc = [&](size_t n) { float* p = ws + off; off += n; return p; };
  const size_t NHE = (size_t)NN * HID_;
  float* hA0 = alloc(NHE); float* hB0 = alloc(NHE);
  float* hA1 = alloc(NHE); float* hB1 = alloc(NHE);
  float* tA = alloc(NHE);  float* tB = alloc(NHE);
  float* QA = alloc(NHE);  float* KAb = alloc(NHE); float* VAb = alloc(NHE);
  float* QB = alloc(NHE);  float* KBb = alloc(NHE); float* VBb = alloc(NHE);
  float* Ap = alloc(NHE);  float* Bp = alloc(NHE);
  float* Opart = alloc((size_t)8 * NN * HID_);
  float* lpart = alloc((size_t)32 * NN);
  float* rvec = alloc(NN);
  float* cvec = alloc(NCOL);
  float* colpart = alloc((size_t)32 * NCOL);
  float* dinvA = alloc(NN); float* dinvB = alloc(NN);
  int* ib = (int*)(ws + off);
  int* cntA = ib;            int* cntB = cntA + NN;
  int* fillA = cntB + NN;    int* fillB = fillA + NN;
  int* rpA = fillB + NN;     int* rpB = rpA + (NN + 1);
  int* srcA = rpB + (NN + 1);int* srcB = srcA + EE;

  float* Lout = (float*)d_out;
  float* Pout = Lout + (size_t)NN * NCOL;
  float* zA = Pout + (size_t)NN * NCOL;
  float* zB = zA + NHE;

  hipMemsetAsync(cntA, 0, 4 * NN * sizeof(int), stream);  // cnt + fill
  hipMemsetAsync(cvec, 0, NCOL * sizeof(float), stream);

  // input projection
  gemm128_k<true, false, false><<<dim3(128, 2), 256, 0, stream>>>(
      A_x, B_x, in_w, in_b, nullptr, nullptr, hA0, hB0);
  // CSR build
  count_deg_k<<<dim3(256, 2), 256, 0, stream>>>(A_ei, B_ei, cntA, cntB);
  scan_k<<<dim3(1, 2), 1024, 0, stream>>>(cntA, cntB, rpA, rpB, dinvA, dinvB);
  fill_k<<<dim3(256, 2), 256, 0, stream>>>(A_ei, B_ei, rpA, rpB, fillA, fillB,
                                           srcA, srcB);
  // GCN encode
  float* hA = hA0; float* hB = hB0; float* aA = hA1; float* aB = hB1;
  for (int l = 0; l < 2; ++l) {
    gemm128_k<false, false, false><<<dim3(128, 2), 256, 0, stream>>>(
        hA, hB, gcn_w + (size_t)l * HID_ * HID_, nullptr, nullptr, nullptr, tA,
        tB);
    gcn_agg_k<<<dim3(1024, 2), 256, 0, stream>>>(
        tA, tB, rpA, rpB, srcA, srcB, dinvA, dinvB, gcn_b + l * HID_,
        lng + l * HID_, lnb + l * HID_, hA, hB);
  }
  // cross attention layers
  for (int l = 0; l < 3; ++l) {
    const float* wq = cq + (size_t)l * HID_ * HID_;
    const float* wk = ck + (size_t)l * HID_ * HID_;
    const float* wv = cv + (size_t)l * HID_ * HID_;
    const float* wo = co + (size_t)l * HID_ * HID_;
    gemm128_k<false, false, false><<<dim3(128, 2), 256, 0, stream>>>(
        hA, hB, wq, nullptr, nullptr, nullptr, QA, QB);
    gemm128_k<false, false, false><<<dim3(128, 2), 256, 0, stream>>>(
        hA, hB, wk, nullptr, nullptr, nullptr, KAb, KBb);
    gemm128_k<false, false, false><<<dim3(128, 2), 256, 0, stream>>>(
        hA, hB, wv, nullptr, nullptr, nullptr, VAb, VBb);
    attn_k<<<dim3(8, 4, 8), 256, 0, stream>>>(QA, KAb, VAb, QB, KBb, VBb,
                                              Opart, lpart);
    attn_combine_k<<<dim3(NN, 2), 128, 0, stream>>>(Opart, lpart, tA, tB);
    gemm128_k<true, false, true><<<dim3(128, 2), 256, 0, stream>>>(
        tA, tB, wo, cob + l * HID_, hA, hB, aA, aB);
    float* t;
    t = hA; hA = aA; aA = t;
    t = hB; hB = aB; aB = t;
  }
  // post-LN + projection
  ln_k<<<dim3(1024, 2), 256, 0, stream>>>(hA, hB, plg, plb);
  gemm128_k<true, false, false><<<dim3(128, 2), 256, 0, stream>>>(
      hA, hB, pw, pb, nullptr, nullptr, Ap, Bp);
  // logits + null column
  gemm_nt_k<<<dim3(64, 64), 256, 0, stream>>>(Ap, Bp, Lout);
  null_col_k<<<NN, 64, 0, stream>>>(Ap, nullv, Lout);
  // sinkhorn (r/c offset form)
  for (int it = 0; it < 20; ++it) {
    sink_row_k<<<NN, 256, 0, stream>>>(Lout, cvec, rvec);
    sink_colp_k<<<dim3(17, 32), 256, 0, stream>>>(Lout, rvec, colpart);
    sink_colc_k<<<17, 256, 0, stream>>>(colpart, cvec);
  }
  sink_final_k<<<NN, 256, 0, stream>>>(Lout, rvec, cvec, Pout);
  // correspondence head
  gemm128_k<true, true, false><<<dim3(128, 2), 256, 0, stream>>>(
      Ap, Bp, w1, b1, nullptr, nullptr, tA, tB);
  gemm128_k<true, false, false><<<dim3(128, 2), 256, 0, stream>>>(
      tA, tB, w2, b2, nullptr, nullptr, zA, zB);
}

// Round 3
// 1233.033 us; speedup vs baseline: 2.1832x; 2.1832x over previous
//
#include <hip/hip_runtime.h>
#include <hip/hip_bf16.h>
#include <math.h>

#define NN 4096
#define EE 65536
#define HID_ 128
#define HDIM 32
#define NCOL 4097

static constexpr float SCALE_ATT = 0.17677669529663687f;   // 1/sqrt(32)
static constexpr float INV_SQRT_D = 0.08838834764831845f;  // 1/sqrt(128)

typedef __attribute__((ext_vector_type(8))) short bf16x8;
typedef __attribute__((ext_vector_type(4))) float f32x4;

__device__ __forceinline__ float wred64(float v) {
#pragma unroll
  for (int m = 32; m > 0; m >>= 1) v += __shfl_xor(v, m, 64);
  return v;
}

__device__ __forceinline__ ushort f2b(float f) {
  __hip_bfloat16 h = __float2bfloat16(f);
  union { __hip_bfloat16 h; ushort u; } c;
  c.h = h;
  return c.u;
}

// ---------------- generic [4096,128] @ [128,128] GEMM, pair-batched ---------
template <bool BIAS, bool RELU, bool RESID>
__global__ __launch_bounds__(256, 2) void gemm128_k(
    const float* __restrict__ x0, const float* __restrict__ x1,
    const float* __restrict__ w, const float* __restrict__ bias,
    const float* __restrict__ res0, const float* __restrict__ res1,
    float* __restrict__ o0, float* __restrict__ o1) {
  const float* x = blockIdx.y ? x1 : x0;
  const float* res = blockIdx.y ? res1 : res0;
  float* out = blockIdx.y ? o1 : o0;
  __shared__ float Xs[32][132];
  __shared__ float Ws[32][128];
  const int tid = threadIdx.x;
  const int rowbase = blockIdx.x * 32;
#pragma unroll
  for (int i = 0; i < 4; ++i) {
    int lin = tid + i * 256;
    int r = lin >> 5, c4 = lin & 31;
    *(float4*)&Xs[r][c4 * 4] =
        *(const float4*)&x[(size_t)(rowbase + r) * HID_ + c4 * 4];
  }
  float acc[4][4] = {};
  const int tr = tid >> 5, tc = tid & 31;
  const int r0 = tr * 4, c0 = tc * 4;
  for (int k0 = 0; k0 < 128; k0 += 32) {
    __syncthreads();
#pragma unroll
    for (int i = 0; i < 4; ++i) {
      int lin = tid + i * 256;
      int r = lin >> 5, c4 = lin & 31;
      *(float4*)&Ws[r][c4 * 4] =
          *(const float4*)&w[(size_t)(k0 + r) * HID_ + c4 * 4];
    }
    __syncthreads();
#pragma unroll
    for (int kk = 0; kk < 32; kk += 4) {
      float4 wv0 = *(const float4*)&Ws[kk + 0][c0];
      float4 wv1 = *(const float4*)&Ws[kk + 1][c0];
      float4 wv2 = *(const float4*)&Ws[kk + 2][c0];
      float4 wv3 = *(const float4*)&Ws[kk + 3][c0];
#pragma unroll
      for (int r = 0; r < 4; ++r) {
        float4 xv = *(const float4*)&Xs[r0 + r][k0 + kk];
        acc[r][0] += xv.x * wv0.x + xv.y * wv1.x + xv.z * wv2.x + xv.w * wv3.x;
        acc[r][1] += xv.x * wv0.y + xv.y * wv1.y + xv.z * wv2.y + xv.w * wv3.y;
        acc[r][2] += xv.x * wv0.z + xv.y * wv1.z + xv.z * wv2.z + xv.w * wv3.z;
        acc[r][3] += xv.x * wv0.w + xv.y * wv1.w + xv.z * wv2.w + xv.w * wv3.w;
      }
    }
  }
  float4 bv = make_float4(0.f, 0.f, 0.f, 0.f);
  if (BIAS) bv = *(const float4*)&bias[c0];
#pragma unroll
  for (int r = 0; r < 4; ++r) {
    size_t orow = (size_t)(rowbase + r0 + r) * HID_ + c0;
    float4 ov;
    ov.x = acc[r][0] + bv.x;
    ov.y = acc[r][1] + bv.y;
    ov.z = acc[r][2] + bv.z;
    ov.w = acc[r][3] + bv.w;
    if (RESID) {
      float4 rv = *(const float4*)&res[orow];
      ov.x += rv.x; ov.y += rv.y; ov.z += rv.z; ov.w += rv.w;
    }
    if (RELU) {
      ov.x = fmaxf(ov.x, 0.f); ov.y = fmaxf(ov.y, 0.f);
      ov.z = fmaxf(ov.z, 0.f); ov.w = fmaxf(ov.w, 0.f);
    }
    *(float4*)&out[orow] = ov;
  }
}

// ---- same GEMM, bf16 output. MODE 0: row-major [4096][128] bf16, scaled.
// ---- MODE 1: transposed [128][4096] bf16 (for V, so PV B-frags are
// ---- kv-contiguous in the attention kernel).
template <int MODE>
__global__ __launch_bounds__(256, 2) void gemm128_bf16_k(
    const float* __restrict__ x0, const float* __restrict__ x1,
    const float* __restrict__ w, float scale, ushort* __restrict__ o0,
    ushort* __restrict__ o1) {
  const float* x = blockIdx.y ? x1 : x0;
  ushort* out = blockIdx.y ? o1 : o0;
  __shared__ float Xs[32][132];
  __shared__ float Ws[32][128];
  const int tid = threadIdx.x;
  const int rowbase = blockIdx.x * 32;
#pragma unroll
  for (int i = 0; i < 4; ++i) {
    int lin = tid + i * 256;
    int r = lin >> 5, c4 = lin & 31;
    *(float4*)&Xs[r][c4 * 4] =
        *(const float4*)&x[(size_t)(rowbase + r) * HID_ + c4 * 4];
  }
  float acc[4][4] = {};
  const int tr = tid >> 5, tc = tid & 31;
  const int r0 = tr * 4, c0 = tc * 4;
  for (int k0 = 0; k0 < 128; k0 += 32) {
    __syncthreads();
#pragma unroll
    for (int i = 0; i < 4; ++i) {
      int lin = tid + i * 256;
      int r = lin >> 5, c4 = lin & 31;
      *(float4*)&Ws[r][c4 * 4] =
          *(const float4*)&w[(size_t)(k0 + r) * HID_ + c4 * 4];
    }
    __syncthreads();
#pragma unroll
    for (int kk = 0; kk < 32; kk += 4) {
      float4 wv0 = *(const float4*)&Ws[kk + 0][c0];
      float4 wv1 = *(const float4*)&Ws[kk + 1][c0];
      float4 wv2 = *(const float4*)&Ws[kk + 2][c0];
      float4 wv3 = *(const float4*)&Ws[kk + 3][c0];
#pragma unroll
      for (int r = 0; r < 4; ++r) {
        float4 xv = *(const float4*)&Xs[r0 + r][k0 + kk];
        acc[r][0] += xv.x * wv0.x + xv.y * wv1.x + xv.z * wv2.x + xv.w * wv3.x;
        acc[r][1] += xv.x * wv0.y + xv.y * wv1.y + xv.z * wv2.y + xv.w * wv3.y;
        acc[r][2] += xv.x * wv0.z + xv.y * wv1.z + xv.z * wv2.z + xv.w * wv3.z;
        acc[r][3] += xv.x * wv0.w + xv.y * wv1.w + xv.z * wv2.w + xv.w * wv3.w;
      }
    }
  }
  if (MODE == 0) {
#pragma unroll
    for (int r = 0; r < 4; ++r) {
      ushort4 pk = make_ushort4(
          f2b(acc[r][0] * scale), f2b(acc[r][1] * scale),
          f2b(acc[r][2] * scale), f2b(acc[r][3] * scale));
      *(ushort4*)&out[(size_t)(rowbase + r0 + r) * HID_ + c0] = pk;
    }
  } else {
#pragma unroll
    for (int r = 0; r < 4; ++r)
#pragma unroll
      for (int c = 0; c < 4; ++c)
        out[(size_t)(c0 + c) * NN + rowbase + r0 + r] = f2b(acc[r][c]);
  }
}

// ---------------- GCN graph build ------------------------------------------
__global__ void count_deg_k(const int* __restrict__ eiA,
                            const int* __restrict__ eiB, int* cntA, int* cntB) {
  int e = blockIdx.x * 256 + threadIdx.x;
  const int* ei = blockIdx.y ? eiB : eiA;
  int* cnt = blockIdx.y ? cntB : cntA;
  atomicAdd(&cnt[ei[EE + e]], 1);
}

__global__ __launch_bounds__(1024) void scan_k(const int* cntA, const int* cntB,
                                               int* rpA, int* rpB, float* dinvA,
                                               float* dinvB) {
  const int* cnt = blockIdx.y ? cntB : cntA;
  int* rp = blockIdx.y ? rpB : rpA;
  float* dinv = blockIdx.y ? dinvB : dinvA;
  __shared__ int part[1024];
  int tid = threadIdx.x;
  int v0 = cnt[tid * 4], v1 = cnt[tid * 4 + 1], v2 = cnt[tid * 4 + 2],
      v3 = cnt[tid * 4 + 3];
  int tot = v0 + v1 + v2 + v3;
  part[tid] = tot;
  __syncthreads();
  int x = tot;
  for (int off = 1; off < 1024; off <<= 1) {
    int y = (tid >= off) ? part[tid - off] : 0;
    __syncthreads();
    x += y;
    part[tid] = x;
    __syncthreads();
  }
  int excl = x - tot;
  rp[tid * 4] = excl;
  rp[tid * 4 + 1] = excl + v0;
  rp[tid * 4 + 2] = excl + v0 + v1;
  rp[tid * 4 + 3] = excl + v0 + v1 + v2;
  if (tid == 1023) rp[4096] = x;
  dinv[tid * 4] = rsqrtf((float)(v0 + 1));
  dinv[tid * 4 + 1] = rsqrtf((float)(v1 + 1));
  dinv[tid * 4 + 2] = rsqrtf((float)(v2 + 1));
  dinv[tid * 4 + 3] = rsqrtf((float)(v3 + 1));
}

__global__ void fill_k(const int* __restrict__ eiA, const int* __restrict__ eiB,
                       const int* rpA, const int* rpB, int* fillA, int* fillB,
                       int* srcA, int* srcB) {
  int e = blockIdx.x * 256 + threadIdx.x;
  const int* ei = blockIdx.y ? eiB : eiA;
  const int* rp = blockIdx.y ? rpB : rpA;
  int* fill = blockIdx.y ? fillB : fillA;
  int* src = blockIdx.y ? srcB : srcA;
  int d = ei[EE + e], s = ei[e];
  int pos = atomicAdd(&fill[d], 1);
  src[rp[d] + pos] = s;
}

// wave-per-node aggregation + bias + LayerNorm + ReLU
__global__ __launch_bounds__(256) void gcn_agg_k(
    const float* __restrict__ xlA, const float* __restrict__ xlB,
    const int* __restrict__ rpA, const int* __restrict__ rpB,
    const int* __restrict__ srcA, const int* __restrict__ srcB,
    const float* __restrict__ dinvA, const float* __restrict__ dinvB,
    const float* __restrict__ gb, const float* __restrict__ lg,
    const float* __restrict__ lb, float* __restrict__ outA,
    float* __restrict__ outB) {
  const float* xl = blockIdx.y ? xlB : xlA;
  const int* rp = blockIdx.y ? rpB : rpA;
  const int* src = blockIdx.y ? srcB : srcA;
  const float* dinv = blockIdx.y ? dinvB : dinvA;
  float* out = blockIdx.y ? outB : outA;
  int wid = threadIdx.x >> 6, lane = threadIdx.x & 63;
  int node = blockIdx.x * 4 + wid;
  int b = rp[node], e = rp[node + 1];
  float di = dinv[node];
  float a0 = 0.f, a1 = 0.f;
  for (int base = b; base < e; base += 64) {
    int rem = e - base;
    int sv = 0;
    float wv = 0.f;
    if (lane < rem) {
      int s = src[base + lane];
      sv = s;
      wv = dinv[s] * di;
    }
    int nch = rem < 64 ? rem : 64;
    for (int j = 0; j < nch; ++j) {
      int s = __shfl(sv, j, 64);
      float w = __shfl(wv, j, 64);
      a0 += xl[(size_t)s * HID_ + lane] * w;
      a1 += xl[(size_t)s * HID_ + 64 + lane] * w;
    }
  }
  a0 += xl[(size_t)node * HID_ + lane] * di * di;
  a1 += xl[(size_t)node * HID_ + 64 + lane] * di * di;
  a0 += gb[lane];
  a1 += gb[64 + lane];
  float mean = wred64(a0 + a1) * (1.f / 128.f);
  float d0 = a0 - mean, d1 = a1 - mean;
  float var = wred64(d0 * d0 + d1 * d1) * (1.f / 128.f);
  float rs = rsqrtf(var + 1e-5f);
  float o0 = d0 * rs * lg[lane] + lb[lane];
  float o1 = d1 * rs * lg[64 + lane] + lb[64 + lane];
  out[(size_t)node * HID_ + lane] = fmaxf(o0, 0.f);
  out[(size_t)node * HID_ + 64 + lane] = fmaxf(o1, 0.f);
}

// ---------------- LayerNorm in-place (wave per row) -------------------------
__global__ __launch_bounds__(256) void ln_k(float* __restrict__ hA,
                                            float* __restrict__ hB,
                                            const float* __restrict__ g,
                                            const float* __restrict__ b) {
  float* h = blockIdx.y ? hB : hA;
  int wid = threadIdx.x >> 6, lane = threadIdx.x & 63;
  int row = blockIdx.x * 4 + wid;
  float a0 = h[(size_t)row * HID_ + lane];
  float a1 = h[(size_t)row * HID_ + 64 + lane];
  float mean = wred64(a0 + a1) * (1.f / 128.f);
  float d0 = a0 - mean, d1 = a1 - mean;
  float var = wred64(d0 * d0 + d1 * d1) * (1.f / 128.f);
  float rs = rsqrtf(var + 1e-5f);
  h[(size_t)row * HID_ + lane] = d0 * rs * g[lane] + b[lane];
  h[(size_t)row * HID_ + 64 + lane] = d1 * rs * g[64 + lane] + b[64 + lane];
}

// ---------------- MFMA attention -------------------------------------------
// grid (64 q-tiles, 4 heads, 2 dirs), 256 threads (4 waves).
// Per block: 64 q-rows; wave w owns q-rows [16w,16w+16).
// Swapped QK^T (mfma(K,Q) -> S^T) so each lane's 4 C-values are contiguous
// kv for ONE q-row -> exp + pack -> one ds_write_b64 into per-wave P tile,
// which feeds PV A-frags with contiguous ds_read_b128. V comes pre-transposed
// ([128][4096] bf16) so PV B-frags are kv-contiguous too.
__global__ __launch_bounds__(256, 2) void attn_mfma_k(
    const ushort* __restrict__ QA, const ushort* __restrict__ KA,
    const ushort* __restrict__ VtA, const ushort* __restrict__ QB,
    const ushort* __restrict__ KB, const ushort* __restrict__ VtB,
    float* __restrict__ outA, float* __restrict__ outB) {
  const int qt = blockIdx.x, h = blockIdx.y, dir = blockIdx.z;
  const ushort* Q = dir ? QB : QA;
  const ushort* K = dir ? KA : KB;
  const ushort* Vt = dir ? VtA : VtB;
  float* out = dir ? outB : outA;

  __shared__ ushort Ks[64 * 40];   // K tile row-major, pad 40 (2-way free)
  __shared__ ushort Vs[32 * 72];   // V^T tile [d][kv], pad 72
  __shared__ ushort Ps[4][16 * 72];// per-wave P tile [q][kv], pad 72

  const int tid = threadIdx.x;
  const int w = tid >> 6, l = tid & 63;
  const int lr = l & 15, lg = l >> 4;

  // Q B-frag: lane l holds Q[q = qt*64 + w*16 + lr][d = lg*8 .. +8]
  const int qrow = qt * 64 + w * 16 + lr;
  bf16x8 qf = *(const bf16x8*)&Q[(size_t)qrow * HID_ + h * HDIM + lg * 8];

  f32x4 oacc0 = {0.f, 0.f, 0.f, 0.f};
  f32x4 oacc1 = {0.f, 0.f, 0.f, 0.f};
  float lpart = 0.f;

  for (int t = 0; t < 64; ++t) {
    const int kv0 = t * 64;
    {  // stage K (64x32) and V^T (32x64)
      int krow = tid >> 2, kch = tid & 3;
      *(bf16x8*)&Ks[krow * 40 + kch * 8] =
          *(const bf16x8*)&K[(size_t)(kv0 + krow) * HID_ + h * HDIM + kch * 8];
      int vd = tid >> 3, vc = tid & 7;
      *(bf16x8*)&Vs[vd * 72 + vc * 8] =
          *(const bf16x8*)&Vt[(size_t)(h * HDIM + vd) * NN + kv0 + vc * 8];
    }
    __syncthreads();
    // S^T = K · Q^T : 4 kv sub-tiles of 16
#pragma unroll
    for (int s = 0; s < 4; ++s) {
      bf16x8 kf = *(const bf16x8*)&Ks[(s * 16 + lr) * 40 + lg * 8];
      f32x4 c = {0.f, 0.f, 0.f, 0.f};
      c = __builtin_amdgcn_mfma_f32_16x16x32_bf16(kf, qf, c, 0, 0, 0);
      float e0 = __expf(c[0]), e1 = __expf(c[1]);
      float e2 = __expf(c[2]), e3 = __expf(c[3]);
      lpart += (e0 + e1) + (e2 + e3);
      ushort4 pk = make_ushort4(f2b(e0), f2b(e1), f2b(e2), f2b(e3));
      // P[q=lr][kv = s*16 + lg*4 .. +4]
      *(ushort4*)&Ps[w][lr * 72 + s * 16 + lg * 4] = pk;
    }
    // PV: O[q][d] += P(16x64) · V(64x32), two K=32 chunks, two d-tiles
#pragma unroll
    for (int k0 = 0; k0 < 2; ++k0) {
      bf16x8 pa = *(const bf16x8*)&Ps[w][lr * 72 + k0 * 32 + lg * 8];
      bf16x8 vb0 = *(const bf16x8*)&Vs[lr * 72 + k0 * 32 + lg * 8];
      bf16x8 vb1 = *(const bf16x8*)&Vs[(16 + lr) * 72 + k0 * 32 + lg * 8];
      oacc0 = __builtin_amdgcn_mfma_f32_16x16x32_bf16(pa, vb0, oacc0, 0, 0, 0);
      oacc1 = __builtin_amdgcn_mfma_f32_16x16x32_bf16(pa, vb1, oacc1, 0, 0, 0);
    }
    __syncthreads();
  }
  // total l per q-row: partials live in the 4 lanes with same (l&15)
  lpart += __shfl_xor(lpart, 16, 64);
  lpart += __shfl_xor(lpart, 32, 64);
  // write O: C-frag row q' = lg*4+r (within wave tile), col = lr
#pragma unroll
  for (int r = 0; r < 4; ++r) {
    int q = qt * 64 + w * 16 + lg * 4 + r;
    float ls = __shfl(lpart, lg * 4 + r, 64);
    float inv = 1.f / ls;
    out[(size_t)q * HID_ + h * HDIM + lr] = oacc0[r] * inv;
    out[(size_t)q * HID_ + h * HDIM + 16 + lr] = oacc1[r] * inv;
  }
}

// ---------------- logits = (Ap @ Bp^T) * inv_sqrt_d -------------------------
__global__ __launch_bounds__(256, 2) void gemm_nt_k(const float* __restrict__ A,
                                                    const float* __restrict__ B,
                                                    float* __restrict__ L) {
  __shared__ float As[64][132];
  __shared__ float BsT[128][68];
  int tid = threadIdx.x;
  int ab = blockIdx.y * 64, bb = blockIdx.x * 64;
#pragma unroll
  for (int i = 0; i < 8; ++i) {
    int lin = tid + i * 256;
    int r = lin >> 5, c4 = lin & 31;
    *(float4*)&As[r][c4 * 4] =
        *(const float4*)&A[(size_t)(ab + r) * HID_ + c4 * 4];
  }
#pragma unroll
  for (int i = 0; i < 32; ++i) {
    int lin = tid + i * 256;
    int r = lin >> 7, k = lin & 127;
    BsT[k][r] = B[(size_t)(bb + r) * HID_ + k];
  }
  __syncthreads();
  int tr = tid >> 4, tc = tid & 15;
  int r0 = tr * 4, c0 = tc * 4;
  float acc[4][4] = {};
#pragma unroll
  for (int k = 0; k < 128; k += 4) {
    float4 bv0 = *(const float4*)&BsT[k + 0][c0];
    float4 bv1 = *(const float4*)&BsT[k + 1][c0];
    float4 bv2 = *(const float4*)&BsT[k + 2][c0];
    float4 bv3 = *(const float4*)&BsT[k + 3][c0];
#pragma unroll
    for (int r = 0; r < 4; ++r) {
      float4 av = *(const float4*)&As[r0 + r][k];
      acc[r][0] += av.x * bv0.x + av.y * bv1.x + av.z * bv2.x + av.w * bv3.x;
      acc[r][1] += av.x * bv0.y + av.y * bv1.y + av.z * bv2.y + av.w * bv3.y;
      acc[r][2] += av.x * bv0.z + av.y * bv1.z + av.z * bv2.z + av.w * bv3.z;
      acc[r][3] += av.x * bv0.w + av.y * bv1.w + av.z * bv2.w + av.w * bv3.w;
    }
  }
#pragma unroll
  for (int r = 0; r < 4; ++r)
#pragma unroll
    for (int c = 0; c < 4; ++c)
      L[(size_t)(ab + r0 + r) * NCOL + bb + c0 + c] = acc[r][c] * INV_SQRT_D;
}

__global__ void null_col_k(const float* __restrict__ Ap,
                           const float* __restrict__ nv,
                           float* __restrict__ L) {
  int row = blockIdx.x, lane = threadIdx.x;
  float s = Ap[(size_t)row * HID_ + lane] * nv[lane] +
            Ap[(size_t)row * HID_ + 64 + lane] * nv[64 + lane];
  s = wred64(s);
  if (lane == 0) L[(size_t)row * NCOL + 4096] = s * INV_SQRT_D;
}

// ---------------- Sinkhorn via r/c offset vectors ---------------------------
__global__ __launch_bounds__(256) void sink_row_k(const float* __restrict__ L,
                                                  const float* __restrict__ c,
                                                  float* __restrict__ r) {
  int row = blockIdx.x, tid = threadIdx.x;
  const float* Lr = L + (size_t)row * NCOL;
  float s = 0.f;
  for (int j = tid; j < NCOL; j += 256) s += __expf(Lr[j] - c[j]);
  s = wred64(s);
  __shared__ float red[4];
  int wid = tid >> 6, lane = tid & 63;
  if (lane == 0) red[wid] = s;
  __syncthreads();
  if (tid == 0) r[row] = __logf(red[0] + red[1] + red[2] + red[3]);
}

__global__ __launch_bounds__(256) void sink_colp_k(const float* __restrict__ L,
                                                   const float* __restrict__ r,
                                                   float* __restrict__ part) {
  int j = blockIdx.x * 256 + threadIdx.x;
  int rc = blockIdx.y;
  if (j >= NCOL) return;
  float s = 0.f;
  int i0 = rc * 128;
#pragma unroll 4
  for (int i = 0; i < 128; ++i)
    s += __expf(L[(size_t)(i0 + i) * NCOL + j] - r[i0 + i]);
  part[(size_t)rc * NCOL + j] = s;
}

__global__ void sink_colc_k(const float* __restrict__ part,
                            float* __restrict__ c) {
  int j = blockIdx.x * 256 + threadIdx.x;
  if (j >= NCOL) return;
  float s = 0.f;
#pragma unroll
  for (int rc = 0; rc < 32; ++rc) s += part[(size_t)rc * NCOL + j];
  c[j] = __logf(s);
}

__global__ __launch_bounds__(256) void sink_final_k(const float* __restrict__ L,
                                                    const float* __restrict__ r,
                                                    const float* __restrict__ c,
                                                    float* __restrict__ P) {
  int row = blockIdx.x;
  float rv = r[row];
  for (int j = threadIdx.x; j < NCOL; j += 256)
    P[(size_t)row * NCOL + j] = __expf(L[(size_t)row * NCOL + j] - rv - c[j]);
}

// ---------------- host ------------------------------------------------------
extern "C" void kernel_launch(void* const* d_in, const int* in_sizes, int n_in,
                              void* d_out, int out_size, void* d_ws,
                              size_t ws_size, hipStream_t stream) {
  const float* A_x = (const float*)d_in[0];
  const int* A_ei = (const int*)d_in[1];
  const float* B_x = (const float*)d_in[2];
  const int* B_ei = (const int*)d_in[3];
  const float* in_w = (const float*)d_in[4];
  const float* in_b = (const float*)d_in[5];
  const float* gcn_w = (const float*)d_in[6];
  const float* gcn_b = (const float*)d_in[7];
  const float* lng = (const float*)d_in[8];
  const float* lnb = (const float*)d_in[9];
  const float* cq = (const float*)d_in[10];
  const float* ck = (const float*)d_in[11];
  const float* cv = (const float*)d_in[12];
  const float* co = (const float*)d_in[13];
  const float* cob = (const float*)d_in[14];
  const float* plg = (const float*)d_in[15];
  const float* plb = (const float*)d_in[16];
  const float* pw = (const float*)d_in[17];
  const float* pb = (const float*)d_in[18];
  const float* nullv = (const float*)d_in[19];
  const float* w1 = (const float*)d_in[20];
  const float* b1 = (const float*)d_in[21];
  const float* w2 = (const float*)d_in[22];
  const float* b2 = (const float*)d_in[23];

  float* ws = (float*)d_ws;
  size_t off = 0;
  auto alloc = [&](size_t n) { float* p = ws + off; off += n; return p; };
  const size_t NHE = (size_t)NN * HID_;
  float* hA0 = alloc(NHE); float* hB0 = alloc(NHE);
  float* hA1 = alloc(NHE); float* hB1 = alloc(NHE);
  float* tA = alloc(NHE);  float* tB = alloc(NHE);
  float* QA = alloc(NHE);  float* KAb = alloc(NHE); float* VAb = alloc(NHE);
  float* QB = alloc(NHE);  float* KBb = alloc(NHE); float* VBb = alloc(NHE);
  float* Ap = alloc(NHE);  float* Bp = alloc(NHE);
  float* rvec = alloc(NN);
  float* cvec = alloc(NCOL);
  float* colpart = alloc((size_t)32 * NCOL);
  float* dinvA = alloc(NN); float* dinvB = alloc(NN);
  int* ib = (int*)(ws + off);
  int* cntA = ib;            int* cntB = cntA + NN;
  int* fillA = cntB + NN;    int* fillB = fillA + NN;
  int* rpA = fillB + NN;     int* rpB = rpA + (NN + 1);
  int* srcA = rpB + (NN + 1);int* srcB = srcA + EE;

  float* Lout = (float*)d_out;
  float* Pout = Lout + (size_t)NN * NCOL;
  float* zA = Pout + (size_t)NN * NCOL;
  float* zB = zA + NHE;

  hipMemsetAsync(cntA, 0, 4 * NN * sizeof(int), stream);  // cnt + fill
  hipMemsetAsync(cvec, 0, NCOL * sizeof(float), stream);

  // input projection
  gemm128_k<true, false, false><<<dim3(128, 2), 256, 0, stream>>>(
      A_x, B_x, in_w, in_b, nullptr, nullptr, hA0, hB0);
  // CSR build
  count_deg_k<<<dim3(256, 2), 256, 0, stream>>>(A_ei, B_ei, cntA, cntB);
  scan_k<<<dim3(1, 2), 1024, 0, stream>>>(cntA, cntB, rpA, rpB, dinvA, dinvB);
  fill_k<<<dim3(256, 2), 256, 0, stream>>>(A_ei, B_ei, rpA, rpB, fillA, fillB,
                                           srcA, srcB);
  // GCN encode
  float* hA = hA0; float* hB = hB0; float* aA = hA1; float* aB = hB1;
  for (int l = 0; l < 2; ++l) {
    gemm128_k<false, false, false><<<dim3(128, 2), 256, 0, stream>>>(
        hA, hB, gcn_w + (size_t)l * HID_ * HID_, nullptr, nullptr, nullptr, tA,
        tB);
    gcn_agg_k<<<dim3(1024, 2), 256, 0, stream>>>(
        tA, tB, rpA, rpB, srcA, srcB, dinvA, dinvB, gcn_b + l * HID_,
        lng + l * HID_, lnb + l * HID_, hA, hB);
  }
  // cross attention layers (bf16 MFMA)
  for (int l = 0; l < 3; ++l) {
    const float* wq = cq + (size_t)l * HID_ * HID_;
    const float* wk = ck + (size_t)l * HID_ * HID_;
    const float* wv = cv + (size_t)l * HID_ * HID_;
    const float* wo = co + (size_t)l * HID_ * HID_;
    gemm128_bf16_k<0><<<dim3(128, 2), 256, 0, stream>>>(
        hA, hB, wq, SCALE_ATT, (ushort*)QA, (ushort*)QB);
    gemm128_bf16_k<0><<<dim3(128, 2), 256, 0, stream>>>(
        hA, hB, wk, 1.f, (ushort*)KAb, (ushort*)KBb);
    gemm128_bf16_k<1><<<dim3(128, 2), 256, 0, stream>>>(
        hA, hB, wv, 1.f, (ushort*)VAb, (ushort*)VBb);
    attn_mfma_k<<<dim3(64, 4, 2), 256, 0, stream>>>(
        (ushort*)QA, (ushort*)KAb, (ushort*)VAb, (ushort*)QB, (ushort*)KBb,
        (ushort*)VBb, tA, tB);
    gemm128_k<true, false, true><<<dim3(128, 2), 256, 0, stream>>>(
        tA, tB, wo, cob + l * HID_, hA, hB, aA, aB);
    float* t;
    t = hA; hA = aA; aA = t;
    t = hB; hB = aB; aB = t;
  }
  // post-LN + projection
  ln_k<<<dim3(1024, 2), 256, 0, stream>>>(hA, hB, plg, plb);
  gemm128_k<true, false, false><<<dim3(128, 2), 256, 0, stream>>>(
      hA, hB, pw, pb, nullptr, nullptr, Ap, Bp);
  // logits + null column
  gemm_nt_k<<<dim3(64, 64), 256, 0, stream>>>(Ap, Bp, Lout);
  null_col_k<<<NN, 64, 0, stream>>>(Ap, nullv, Lout);
  // sinkhorn (r/c offset form)
  for (int it = 0; it < 20; ++it) {
    sink_row_k<<<NN, 256, 0, stream>>>(Lout, cvec, rvec);
    sink_colp_k<<<dim3(17, 32), 256, 0, stream>>>(Lout, rvec, colpart);
    sink_colc_k<<<17, 256, 0, stream>>>(colpart, cvec);
  }
  sink_final_k<<<NN, 256, 0, stream>>>(Lout, rvec, cvec, Pout);
  // correspondence head
  gemm128_k<true, true, false><<<dim3(128, 2), 256, 0, stream>>>(
      Ap, Bp, w1, b1, nullptr, nullptr, tA, tB);
  gemm128_k<true, false, false><<<dim3(128, 2), 256, 0, stream>>>(
      tA, tB, w2, b2, nullptr, nullptr, zA, zB);
}

// Round 4
// 1121.413 us; speedup vs baseline: 2.4005x; 1.0995x over previous
//
#include <hip/hip_runtime.h>
#include <hip/hip_bf16.h>
#include <math.h>

#define NN 4096
#define EE 65536
#define HID_ 128
#define HDIM 32
#define NCOL 4097
#define EHP 4104  // Eh padded row stride (halfs), 16B-aligned rows

static constexpr float SCALE_ATT = 0.17677669529663687f;   // 1/sqrt(32)
static constexpr float INV_SQRT_D = 0.08838834764831845f;  // 1/sqrt(128)
static constexpr float LOG2E = 1.4426950408889634f;

typedef __attribute__((ext_vector_type(8))) short bf16x8;
typedef __attribute__((ext_vector_type(4))) float f32x4;
typedef _Float16 half8 __attribute__((ext_vector_type(8)));
typedef _Float16 half2v __attribute__((ext_vector_type(2)));

__device__ __forceinline__ float wred64(float v) {
#pragma unroll
  for (int m = 32; m > 0; m >>= 1) v += __shfl_xor(v, m, 64);
  return v;
}

__device__ __forceinline__ ushort f2b(float f) {
  __hip_bfloat16 h = __float2bfloat16(f);
  union { __hip_bfloat16 h; ushort u; } c;
  c.h = h;
  return c.u;
}

// ---------------- generic [4096,128] @ [128,128] GEMM, pair-batched ---------
template <bool BIAS, bool RELU, bool RESID>
__global__ __launch_bounds__(256, 2) void gemm128_k(
    const float* __restrict__ x0, const float* __restrict__ x1,
    const float* __restrict__ w, const float* __restrict__ bias,
    const float* __restrict__ res0, const float* __restrict__ res1,
    float* __restrict__ o0, float* __restrict__ o1) {
  const float* x = blockIdx.y ? x1 : x0;
  const float* res = blockIdx.y ? res1 : res0;
  float* out = blockIdx.y ? o1 : o0;
  __shared__ float Xs[32][132];
  __shared__ float Ws[32][128];
  const int tid = threadIdx.x;
  const int rowbase = blockIdx.x * 32;
#pragma unroll
  for (int i = 0; i < 4; ++i) {
    int lin = tid + i * 256;
    int r = lin >> 5, c4 = lin & 31;
    *(float4*)&Xs[r][c4 * 4] =
        *(const float4*)&x[(size_t)(rowbase + r) * HID_ + c4 * 4];
  }
  float acc[4][4] = {};
  const int tr = tid >> 5, tc = tid & 31;
  const int r0 = tr * 4, c0 = tc * 4;
  for (int k0 = 0; k0 < 128; k0 += 32) {
    __syncthreads();
#pragma unroll
    for (int i = 0; i < 4; ++i) {
      int lin = tid + i * 256;
      int r = lin >> 5, c4 = lin & 31;
      *(float4*)&Ws[r][c4 * 4] =
          *(const float4*)&w[(size_t)(k0 + r) * HID_ + c4 * 4];
    }
    __syncthreads();
#pragma unroll
    for (int kk = 0; kk < 32; kk += 4) {
      float4 wv0 = *(const float4*)&Ws[kk + 0][c0];
      float4 wv1 = *(const float4*)&Ws[kk + 1][c0];
      float4 wv2 = *(const float4*)&Ws[kk + 2][c0];
      float4 wv3 = *(const float4*)&Ws[kk + 3][c0];
#pragma unroll
      for (int r = 0; r < 4; ++r) {
        float4 xv = *(const float4*)&Xs[r0 + r][k0 + kk];
        acc[r][0] += xv.x * wv0.x + xv.y * wv1.x + xv.z * wv2.x + xv.w * wv3.x;
        acc[r][1] += xv.x * wv0.y + xv.y * wv1.y + xv.z * wv2.y + xv.w * wv3.y;
        acc[r][2] += xv.x * wv0.z + xv.y * wv1.z + xv.z * wv2.z + xv.w * wv3.z;
        acc[r][3] += xv.x * wv0.w + xv.y * wv1.w + xv.z * wv2.w + xv.w * wv3.w;
      }
    }
  }
  float4 bv = make_float4(0.f, 0.f, 0.f, 0.f);
  if (BIAS) bv = *(const float4*)&bias[c0];
#pragma unroll
  for (int r = 0; r < 4; ++r) {
    size_t orow = (size_t)(rowbase + r0 + r) * HID_ + c0;
    float4 ov;
    ov.x = acc[r][0] + bv.x;
    ov.y = acc[r][1] + bv.y;
    ov.z = acc[r][2] + bv.z;
    ov.w = acc[r][3] + bv.w;
    if (RESID) {
      float4 rv = *(const float4*)&res[orow];
      ov.x += rv.x; ov.y += rv.y; ov.z += rv.z; ov.w += rv.w;
    }
    if (RELU) {
      ov.x = fmaxf(ov.x, 0.f); ov.y = fmaxf(ov.y, 0.f);
      ov.z = fmaxf(ov.z, 0.f); ov.w = fmaxf(ov.w, 0.f);
    }
    *(float4*)&out[orow] = ov;
  }
}

// ---- same GEMM, bf16 output. MODE 0: row-major [4096][128] bf16, scaled.
// ---- MODE 1: transposed [128][4096] bf16 (V).
template <int MODE>
__global__ __launch_bounds__(256, 2) void gemm128_bf16_k(
    const float* __restrict__ x0, const float* __restrict__ x1,
    const float* __restrict__ w, float scale, ushort* __restrict__ o0,
    ushort* __restrict__ o1) {
  const float* x = blockIdx.y ? x1 : x0;
  ushort* out = blockIdx.y ? o1 : o0;
  __shared__ float Xs[32][132];
  __shared__ float Ws[32][128];
  const int tid = threadIdx.x;
  const int rowbase = blockIdx.x * 32;
#pragma unroll
  for (int i = 0; i < 4; ++i) {
    int lin = tid + i * 256;
    int r = lin >> 5, c4 = lin & 31;
    *(float4*)&Xs[r][c4 * 4] =
        *(const float4*)&x[(size_t)(rowbase + r) * HID_ + c4 * 4];
  }
  float acc[4][4] = {};
  const int tr = tid >> 5, tc = tid & 31;
  const int r0 = tr * 4, c0 = tc * 4;
  for (int k0 = 0; k0 < 128; k0 += 32) {
    __syncthreads();
#pragma unroll
    for (int i = 0; i < 4; ++i) {
      int lin = tid + i * 256;
      int r = lin >> 5, c4 = lin & 31;
      *(float4*)&Ws[r][c4 * 4] =
          *(const float4*)&w[(size_t)(k0 + r) * HID_ + c4 * 4];
    }
    __syncthreads();
#pragma unroll
    for (int kk = 0; kk < 32; kk += 4) {
      float4 wv0 = *(const float4*)&Ws[kk + 0][c0];
      float4 wv1 = *(const float4*)&Ws[kk + 1][c0];
      float4 wv2 = *(const float4*)&Ws[kk + 2][c0];
      float4 wv3 = *(const float4*)&Ws[kk + 3][c0];
#pragma unroll
      for (int r = 0; r < 4; ++r) {
        float4 xv = *(const float4*)&Xs[r0 + r][k0 + kk];
        acc[r][0] += xv.x * wv0.x + xv.y * wv1.x + xv.z * wv2.x + xv.w * wv3.x;
        acc[r][1] += xv.x * wv0.y + xv.y * wv1.y + xv.z * wv2.y + xv.w * wv3.y;
        acc[r][2] += xv.x * wv0.z + xv.y * wv1.z + xv.z * wv2.z + xv.w * wv3.z;
        acc[r][3] += xv.x * wv0.w + xv.y * wv1.w + xv.z * wv2.w + xv.w * wv3.w;
      }
    }
  }
  if (MODE == 0) {
#pragma unroll
    for (int r = 0; r < 4; ++r) {
      ushort4 pk = make_ushort4(
          f2b(acc[r][0] * scale), f2b(acc[r][1] * scale),
          f2b(acc[r][2] * scale), f2b(acc[r][3] * scale));
      *(ushort4*)&out[(size_t)(rowbase + r0 + r) * HID_ + c0] = pk;
    }
  } else {
#pragma unroll
    for (int r = 0; r < 4; ++r)
#pragma unroll
      for (int c = 0; c < 4; ++c)
        out[(size_t)(c0 + c) * NN + rowbase + r0 + r] = f2b(acc[r][c]);
  }
}

// ---------------- GCN graph build ------------------------------------------
__global__ void count_deg_k(const int* __restrict__ eiA,
                            const int* __restrict__ eiB, int* cntA, int* cntB) {
  int e = blockIdx.x * 256 + threadIdx.x;
  const int* ei = blockIdx.y ? eiB : eiA;
  int* cnt = blockIdx.y ? cntB : cntA;
  atomicAdd(&cnt[ei[EE + e]], 1);
}

__global__ __launch_bounds__(1024) void scan_k(const int* cntA, const int* cntB,
                                               int* rpA, int* rpB, float* dinvA,
                                               float* dinvB) {
  const int* cnt = blockIdx.y ? cntB : cntA;
  int* rp = blockIdx.y ? rpB : rpA;
  float* dinv = blockIdx.y ? dinvB : dinvA;
  __shared__ int part[1024];
  int tid = threadIdx.x;
  int v0 = cnt[tid * 4], v1 = cnt[tid * 4 + 1], v2 = cnt[tid * 4 + 2],
      v3 = cnt[tid * 4 + 3];
  int tot = v0 + v1 + v2 + v3;
  part[tid] = tot;
  __syncthreads();
  int x = tot;
  for (int off = 1; off < 1024; off <<= 1) {
    int y = (tid >= off) ? part[tid - off] : 0;
    __syncthreads();
    x += y;
    part[tid] = x;
    __syncthreads();
  }
  int excl = x - tot;
  rp[tid * 4] = excl;
  rp[tid * 4 + 1] = excl + v0;
  rp[tid * 4 + 2] = excl + v0 + v1;
  rp[tid * 4 + 3] = excl + v0 + v1 + v2;
  if (tid == 1023) rp[4096] = x;
  dinv[tid * 4] = rsqrtf((float)(v0 + 1));
  dinv[tid * 4 + 1] = rsqrtf((float)(v1 + 1));
  dinv[tid * 4 + 2] = rsqrtf((float)(v2 + 1));
  dinv[tid * 4 + 3] = rsqrtf((float)(v3 + 1));
}

__global__ void fill_k(const int* __restrict__ eiA, const int* __restrict__ eiB,
                       const int* rpA, const int* rpB, int* fillA, int* fillB,
                       int* srcA, int* srcB) {
  int e = blockIdx.x * 256 + threadIdx.x;
  const int* ei = blockIdx.y ? eiB : eiA;
  const int* rp = blockIdx.y ? rpB : rpA;
  int* fill = blockIdx.y ? fillB : fillA;
  int* src = blockIdx.y ? srcB : srcA;
  int d = ei[EE + e], s = ei[e];
  int pos = atomicAdd(&fill[d], 1);
  src[rp[d] + pos] = s;
}

// wave-per-node aggregation + bias + LayerNorm + ReLU
__global__ __launch_bounds__(256) void gcn_agg_k(
    const float* __restrict__ xlA, const float* __restrict__ xlB,
    const int* __restrict__ rpA, const int* __restrict__ rpB,
    const int* __restrict__ srcA, const int* __restrict__ srcB,
    const float* __restrict__ dinvA, const float* __restrict__ dinvB,
    const float* __restrict__ gb, const float* __restrict__ lg,
    const float* __restrict__ lb, float* __restrict__ outA,
    float* __restrict__ outB) {
  const float* xl = blockIdx.y ? xlB : xlA;
  const int* rp = blockIdx.y ? rpB : rpA;
  const int* src = blockIdx.y ? srcB : srcA;
  const float* dinv = blockIdx.y ? dinvB : dinvA;
  float* out = blockIdx.y ? outB : outA;
  int wid = threadIdx.x >> 6, lane = threadIdx.x & 63;
  int node = blockIdx.x * 4 + wid;
  int b = rp[node], e = rp[node + 1];
  float di = dinv[node];
  float a0 = 0.f, a1 = 0.f;
  for (int base = b; base < e; base += 64) {
    int rem = e - base;
    int sv = 0;
    float wv = 0.f;
    if (lane < rem) {
      int s = src[base + lane];
      sv = s;
      wv = dinv[s] * di;
    }
    int nch = rem < 64 ? rem : 64;
    for (int j = 0; j < nch; ++j) {
      int s = __shfl(sv, j, 64);
      float w = __shfl(wv, j, 64);
      a0 += xl[(size_t)s * HID_ + lane] * w;
      a1 += xl[(size_t)s * HID_ + 64 + lane] * w;
    }
  }
  a0 += xl[(size_t)node * HID_ + lane] * di * di;
  a1 += xl[(size_t)node * HID_ + 64 + lane] * di * di;
  a0 += gb[lane];
  a1 += gb[64 + lane];
  float mean = wred64(a0 + a1) * (1.f / 128.f);
  float d0 = a0 - mean, d1 = a1 - mean;
  float var = wred64(d0 * d0 + d1 * d1) * (1.f / 128.f);
  float rs = rsqrtf(var + 1e-5f);
  float o0 = d0 * rs * lg[lane] + lb[lane];
  float o1 = d1 * rs * lg[64 + lane] + lb[64 + lane];
  out[(size_t)node * HID_ + lane] = fmaxf(o0, 0.f);
  out[(size_t)node * HID_ + 64 + lane] = fmaxf(o1, 0.f);
}

// ---------------- LayerNorm in-place (wave per row) -------------------------
__global__ __launch_bounds__(256) void ln_k(float* __restrict__ hA,
                                            float* __restrict__ hB,
                                            const float* __restrict__ g,
                                            const float* __restrict__ b) {
  float* h = blockIdx.y ? hB : hA;
  int wid = threadIdx.x >> 6, lane = threadIdx.x & 63;
  int row = blockIdx.x * 4 + wid;
  float a0 = h[(size_t)row * HID_ + lane];
  float a1 = h[(size_t)row * HID_ + 64 + lane];
  float mean = wred64(a0 + a1) * (1.f / 128.f);
  float d0 = a0 - mean, d1 = a1 - mean;
  float var = wred64(d0 * d0 + d1 * d1) * (1.f / 128.f);
  float rs = rsqrtf(var + 1e-5f);
  h[(size_t)row * HID_ + lane] = d0 * rs * g[lane] + b[lane];
  h[(size_t)row * HID_ + 64 + lane] = d1 * rs * g[64 + lane] + b[64 + lane];
}

// ---------------- MFMA attention, fragment-ordered LDS ----------------------
// grid (64 q-tiles, 4 heads, 2 dirs), 256 threads (4 waves).
// All ds_read_b128 hit dword offset (const + l*4): canonical conflict-free.
// Q pre-scaled by SCALE*log2e -> exp2f for softmax.
__global__ __launch_bounds__(256, 2) void attn_mfma_k(
    const ushort* __restrict__ QA, const ushort* __restrict__ KA,
    const ushort* __restrict__ VtA, const ushort* __restrict__ QB,
    const ushort* __restrict__ KB, const ushort* __restrict__ VtB,
    float* __restrict__ outA, float* __restrict__ outB) {
  const int qt = blockIdx.x, h = blockIdx.y, dir = blockIdx.z;
  const ushort* Q = dir ? QB : QA;
  const ushort* K = dir ? KA : KB;
  const ushort* Vt = dir ? VtA : VtB;
  float* out = dir ? outB : outA;

  __shared__ ushort KF[2048];     // frag order: [s][lg][lr][8]
  __shared__ ushort VF[2048];     // frag order: [dt*2+k0][lg][lr][8]
  __shared__ ushort PF[4][1024];  // per-wave:  [k0][lgr][lr][8]

  const int tid = threadIdx.x;
  const int w = tid >> 6, l = tid & 63;
  const int lr = l & 15, lg = l >> 4;

  const int qrow = qt * 64 + w * 16 + lr;
  bf16x8 qf = *(const bf16x8*)&Q[(size_t)qrow * HID_ + h * HDIM + lg * 8];

  f32x4 oacc0 = {0.f, 0.f, 0.f, 0.f};
  f32x4 oacc1 = {0.f, 0.f, 0.f, 0.f};
  float lpart = 0.f;

  const int ldst = ((w * 4 + lg) * 16 + lr) * 8;  // lds write slot (dword l*4+w*256)
  const ushort* Kg = K + (size_t)(w * 16 + lr) * HID_ + h * HDIM + lg * 8;
  const ushort* Vg =
      Vt + (size_t)(h * HDIM + (w >> 1) * 16 + lr) * NN + (w & 1) * 32 + lg * 8;

  for (int t = 0; t < 64; ++t) {
    const int kv0 = t * 64;
    __syncthreads();
    *(bf16x8*)&KF[ldst] = *(const bf16x8*)&Kg[(size_t)kv0 * HID_];
    *(bf16x8*)&VF[ldst] = *(const bf16x8*)&Vg[kv0];
    __syncthreads();
    // S^T = K * Q^T, 4 kv sub-tiles of 16
#pragma unroll
    for (int s = 0; s < 4; ++s) {
      bf16x8 kf = *(const bf16x8*)&KF[((s * 4 + lg) * 16 + lr) * 8];
      f32x4 c = {0.f, 0.f, 0.f, 0.f};
      c = __builtin_amdgcn_mfma_f32_16x16x32_bf16(kf, qf, c, 0, 0, 0);
      float e0 = exp2f(c[0]), e1 = exp2f(c[1]);
      float e2 = exp2f(c[2]), e3 = exp2f(c[3]);
      lpart += (e0 + e1) + (e2 + e3);
      ushort4 pk = make_ushort4(f2b(e0), f2b(e1), f2b(e2), f2b(e3));
      const int k0 = s >> 1;
      const int lgr = (s & 1) * 2 + (lg >> 1);
      const int e8 = (lg & 1) * 4;
      *(ushort4*)&PF[w][((k0 * 4 + lgr) * 16 + lr) * 8 + e8] = pk;
    }
    // PV: O[q][d] += P(16x64) * V(64x32)
#pragma unroll
    for (int k0 = 0; k0 < 2; ++k0) {
      bf16x8 pa = *(const bf16x8*)&PF[w][((k0 * 4 + lg) * 16 + lr) * 8];
      bf16x8 vb0 = *(const bf16x8*)&VF[((k0 * 4 + lg) * 16 + lr) * 8];
      bf16x8 vb1 = *(const bf16x8*)&VF[(((2 + k0) * 4 + lg) * 16 + lr) * 8];
      oacc0 = __builtin_amdgcn_mfma_f32_16x16x32_bf16(pa, vb0, oacc0, 0, 0, 0);
      oacc1 = __builtin_amdgcn_mfma_f32_16x16x32_bf16(pa, vb1, oacc1, 0, 0, 0);
    }
  }
  lpart += __shfl_xor(lpart, 16, 64);
  lpart += __shfl_xor(lpart, 32, 64);
#pragma unroll
  for (int r = 0; r < 4; ++r) {
    int q = qt * 64 + w * 16 + lg * 4 + r;
    float ls = __shfl(lpart, lg * 4 + r, 64);
    float inv = 1.f / ls;
    out[(size_t)q * HID_ + h * HDIM + lr] = oacc0[r] * inv;
    out[(size_t)q * HID_ + h * HDIM + 16 + lr] = oacc1[r] * inv;
  }
}

// ---------------- cast Ap/Bp fp32 -> bf16 -----------------------------------
__global__ void castf2b_k(const float* __restrict__ A,
                          const float* __restrict__ B, ushort* __restrict__ Ab,
                          ushort* __restrict__ Bb) {
  int i = (blockIdx.x * 256 + threadIdx.x) * 8;
  float4 a0 = *(const float4*)&A[i];
  float4 a1 = *(const float4*)&A[i + 4];
  *(ushort4*)&Ab[i] = make_ushort4(f2b(a0.x), f2b(a0.y), f2b(a0.z), f2b(a0.w));
  *(ushort4*)&Ab[i + 4] =
      make_ushort4(f2b(a1.x), f2b(a1.y), f2b(a1.z), f2b(a1.w));
  float4 b0 = *(const float4*)&B[i];
  float4 b1 = *(const float4*)&B[i + 4];
  *(ushort4*)&Bb[i] = make_ushort4(f2b(b0.x), f2b(b0.y), f2b(b0.z), f2b(b0.w));
  *(ushort4*)&Bb[i + 4] =
      make_ushort4(f2b(b1.x), f2b(b1.y), f2b(b1.z), f2b(b1.w));
}

// ---------------- logits via bf16 MFMA + fused Eh=exp(L) epilogue -----------
// 128x128 tile, 4 waves, XOR-swizzled 16B chunks in LDS.
__global__ __launch_bounds__(256, 2) void gemm_nt_mfma_k(
    const ushort* __restrict__ Apb, const ushort* __restrict__ Bpb,
    float* __restrict__ L, _Float16* __restrict__ Eh) {
  __shared__ ushort As[128 * 128];
  __shared__ ushort Bs[128 * 128];
  const int tid = threadIdx.x;
  const int ab = blockIdx.y * 128, bb = blockIdx.x * 128;
#pragma unroll
  for (int i = 0; i < 8; ++i) {
    int lin = tid + i * 256;
    int row = lin >> 4, ch = lin & 15;
    int pch = ch ^ (row & 15);
    *(bf16x8*)&As[row * 128 + pch * 8] =
        *(const bf16x8*)&Apb[(size_t)(ab + row) * HID_ + ch * 8];
    *(bf16x8*)&Bs[row * 128 + pch * 8] =
        *(const bf16x8*)&Bpb[(size_t)(bb + row) * HID_ + ch * 8];
  }
  __syncthreads();
  const int w = tid >> 6, l = tid & 63, lr = l & 15, lg = l >> 4;
  f32x4 acc[2][8];
#pragma unroll
  for (int fm = 0; fm < 2; ++fm)
#pragma unroll
    for (int nf = 0; nf < 8; ++nf) acc[fm][nf] = {0.f, 0.f, 0.f, 0.f};
#pragma unroll
  for (int kc = 0; kc < 4; ++kc) {
    bf16x8 a0 = *(const bf16x8*)
        &As[((w * 2 + 0) * 16 + lr) * 128 + ((kc * 4 + lg) ^ lr) * 8];
    bf16x8 a1 = *(const bf16x8*)
        &As[((w * 2 + 1) * 16 + lr) * 128 + ((kc * 4 + lg) ^ lr) * 8];
#pragma unroll
    for (int nf = 0; nf < 8; ++nf) {
      bf16x8 bf = *(const bf16x8*)
          &Bs[(nf * 16 + lr) * 128 + ((kc * 4 + lg) ^ lr) * 8];
      acc[0][nf] = __builtin_amdgcn_mfma_f32_16x16x32_bf16(a0, bf, acc[0][nf], 0, 0, 0);
      acc[1][nf] = __builtin_amdgcn_mfma_f32_16x16x32_bf16(a1, bf, acc[1][nf], 0, 0, 0);
    }
  }
#pragma unroll
  for (int fm = 0; fm < 2; ++fm)
#pragma unroll
    for (int nf = 0; nf < 8; ++nf)
#pragma unroll
      for (int r = 0; r < 4; ++r) {
        int row = ab + (w * 2 + fm) * 16 + lg * 4 + r;
        int col = bb + nf * 16 + lr;
        float v = acc[fm][nf][r] * INV_SQRT_D;
        L[(size_t)row * NCOL + col] = v;
        Eh[(size_t)row * EHP + col] = (_Float16)exp2f(v * LOG2E);
      }
}

__global__ void null_col_k(const float* __restrict__ Ap,
                           const float* __restrict__ nv, float* __restrict__ L,
                           _Float16* __restrict__ Eh) {
  int row = blockIdx.x, lane = threadIdx.x;
  float s = Ap[(size_t)row * HID_ + lane] * nv[lane] +
            Ap[(size_t)row * HID_ + 64 + lane] * nv[64 + lane];
  s = wred64(s);
  if (lane == 0) {
    float v = s * INV_SQRT_D;
    L[(size_t)row * NCOL + 4096] = v;
    Eh[(size_t)row * EHP + 4096] = (_Float16)exp2f(v * LOG2E);
  }
  if (lane >= 1 && lane < 8) Eh[(size_t)row * EHP + 4096 + lane] = (_Float16)0.f;
}

// ---------------- Sinkhorn: u/v matvec form on fp16 E -----------------------
__global__ void sink_init_k(float* t0) {
  int j = blockIdx.x * 256 + threadIdx.x;
  if (j < EHP) t0[j] = 1.f;
}

// u_i = 1 / sum_j Eh[i][j] * v_j, with v = 1/t_old staged in LDS.
// Also zeroes t_new (blocks 0..16) for the following column pass.
__global__ __launch_bounds__(256) void sink_rowm_k(
    const _Float16* __restrict__ Eh, const float* __restrict__ t_old,
    float* __restrict__ t_new, float* __restrict__ u) {
  __shared__ float vls[EHP];
  int tid = threadIdx.x;
  if (blockIdx.x < 17) {
    int j = blockIdx.x * 256 + tid;
    if (j < EHP) t_new[j] = 0.f;
  }
  for (int i = tid; i < EHP; i += 256)
    vls[i] = (i < NCOL) ? (1.f / t_old[i]) : 0.f;
  __syncthreads();
  int w = tid >> 6, l = tid & 63;
  for (int rr = 0; rr < 4; ++rr) {
    int row = blockIdx.x * 16 + w * 4 + rr;
    const _Float16* Ep = Eh + (size_t)row * EHP;
    float s = 0.f;
    for (int j = l * 8; j < EHP; j += 512) {
      half8 e = *(const half8*)&Ep[j];
#pragma unroll
      for (int k = 0; k < 8; ++k) s += (float)e[k] * vls[j + k];
    }
    s = wred64(s);
    if (l == 0) u[row] = 1.f / s;
  }
}

// t_j += sum_i Eh[i][j] * u_i over a 64-row chunk (atomic accumulate).
__global__ __launch_bounds__(256) void sink_colm_k(
    const _Float16* __restrict__ Eh, const float* __restrict__ u,
    float* __restrict__ t_new) {
  __shared__ float uls[64];
  int tid = threadIdx.x;
  int i0 = blockIdx.y * 64;
  if (tid < 64) uls[tid] = u[i0 + tid];
  __syncthreads();
  int j0 = (blockIdx.x * 256 + tid) * 2;
  if (j0 >= EHP) return;
  float s0 = 0.f, s1 = 0.f;
#pragma unroll 8
  for (int i = 0; i < 64; ++i) {
    half2v e = *(const half2v*)&Eh[(size_t)(i0 + i) * EHP + j0];
    s0 += (float)e[0] * uls[i];
    s1 += (float)e[1] * uls[i];
  }
  atomicAdd(&t_new[j0], s0);
  atomicAdd(&t_new[j0 + 1], s1);
}

// P = Eh * u_i * (1/t_j)
__global__ __launch_bounds__(256) void sink_finalE_k(
    const _Float16* __restrict__ Eh, const float* __restrict__ u,
    const float* __restrict__ t, float* __restrict__ P) {
  __shared__ float vls[NCOL];
  int tid = threadIdx.x, row = blockIdx.x;
  for (int i = tid; i < NCOL; i += 256) vls[i] = 1.f / t[i];
  __syncthreads();
  float ur = u[row];
  const _Float16* Ep = Eh + (size_t)row * EHP;
  float* Pp = P + (size_t)row * NCOL;
  for (int j = tid; j < NCOL; j += 256) Pp[j] = (float)Ep[j] * ur * vls[j];
}

// ---------------- host ------------------------------------------------------
extern "C" void kernel_launch(void* const* d_in, const int* in_sizes, int n_in,
                              void* d_out, int out_size, void* d_ws,
                              size_t ws_size, hipStream_t stream) {
  const float* A_x = (const float*)d_in[0];
  const int* A_ei = (const int*)d_in[1];
  const float* B_x = (const float*)d_in[2];
  const int* B_ei = (const int*)d_in[3];
  const float* in_w = (const float*)d_in[4];
  const float* in_b = (const float*)d_in[5];
  const float* gcn_w = (const float*)d_in[6];
  const float* gcn_b = (const float*)d_in[7];
  const float* lng = (const float*)d_in[8];
  const float* lnb = (const float*)d_in[9];
  const float* cq = (const float*)d_in[10];
  const float* ck = (const float*)d_in[11];
  const float* cv = (const float*)d_in[12];
  const float* co = (const float*)d_in[13];
  const float* cob = (const float*)d_in[14];
  const float* plg = (const float*)d_in[15];
  const float* plb = (const float*)d_in[16];
  const float* pw = (const float*)d_in[17];
  const float* pb = (const float*)d_in[18];
  const float* nullv = (const float*)d_in[19];
  const float* w1 = (const float*)d_in[20];
  const float* b1 = (const float*)d_in[21];
  const float* w2 = (const float*)d_in[22];
  const float* b2 = (const float*)d_in[23];

  float* ws = (float*)d_ws;
  size_t off = 0;
  auto alloc = [&](size_t n) { float* p = ws + off; off += n; return p; };
  const size_t NHE = (size_t)NN * HID_;
  // --- persistent zone (alive across sinkhorn) ---
  float* tA = alloc(NHE);
  float* tB = alloc(NHE);
  float* Ap = alloc(NHE);
  float* Bp = alloc(NHE);
  ushort* Apb = (ushort*)alloc(NHE / 2);
  ushort* Bpb = (ushort*)alloc(NHE / 2);
  float* uvec = alloc(NN);
  float* t0 = alloc(EHP);
  float* t1 = alloc(EHP);
  // --- overlay zone: encoder/attention buffers, later reused as Eh ---
  float* zone = ws + off;
  float* hA0 = alloc(NHE); float* hB0 = alloc(NHE);
  float* hA1 = alloc(NHE); float* hB1 = alloc(NHE);
  float* QA = alloc(NHE);  float* KAb = alloc(NHE); float* VAb = alloc(NHE);
  float* QB = alloc(NHE);  float* KBb = alloc(NHE); float* VBb = alloc(NHE);
  float* dinvA = alloc(NN); float* dinvB = alloc(NN);
  int* ib = (int*)(ws + off);
  int* cntA = ib;             int* cntB = cntA + NN;
  int* fillA = cntB + NN;     int* fillB = fillA + NN;
  int* rpA = fillB + NN;      int* rpB = rpA + (NN + 1);
  int* srcA = rpB + (NN + 1); int* srcB = srcA + EE;
  // Eh overlays the zone (33.6 MB > zone's named 21.7 MB; extend off to cover)
  _Float16* Eh = (_Float16*)zone;
  {
    size_t zone_used = (size_t)(ws + off - zone) + (2 * EE + 4 * NN + 2 * (NN + 1)) / 1;
    size_t eh_floats = ((size_t)NN * EHP + 1) / 2;
    size_t zone_named = (size_t)((ws + off) - zone);  // floats, ints not counted
    (void)zone_used; (void)zone_named;
    // advance off past max(named+ints, Eh)
    size_t ints_floats = (size_t)(4 * NN + 2 * (NN + 1) + 2 * EE);
    size_t named = (size_t)((ws + off) - zone) + ints_floats;
    size_t need = eh_floats > named ? eh_floats : named;
    off = (size_t)(zone - ws) + need;
  }

  float* Lout = (float*)d_out;
  float* Pout = Lout + (size_t)NN * NCOL;
  float* zA = Pout + (size_t)NN * NCOL;
  float* zB = zA + NHE;

  hipMemsetAsync(cntA, 0, 4 * NN * sizeof(int), stream);  // cnt + fill

  // input projection
  gemm128_k<true, false, false><<<dim3(128, 2), 256, 0, stream>>>(
      A_x, B_x, in_w, in_b, nullptr, nullptr, hA0, hB0);
  // CSR build
  count_deg_k<<<dim3(256, 2), 256, 0, stream>>>(A_ei, B_ei, cntA, cntB);
  scan_k<<<dim3(1, 2), 1024, 0, stream>>>(cntA, cntB, rpA, rpB, dinvA, dinvB);
  fill_k<<<dim3(256, 2), 256, 0, stream>>>(A_ei, B_ei, rpA, rpB, fillA, fillB,
                                           srcA, srcB);
  // GCN encode
  float* hA = hA0; float* hB = hB0; float* aA = hA1; float* aB = hB1;
  for (int l = 0; l < 2; ++l) {
    gemm128_k<false, false, false><<<dim3(128, 2), 256, 0, stream>>>(
        hA, hB, gcn_w + (size_t)l * HID_ * HID_, nullptr, nullptr, nullptr, tA,
        tB);
    gcn_agg_k<<<dim3(1024, 2), 256, 0, stream>>>(
        tA, tB, rpA, rpB, srcA, srcB, dinvA, dinvB, gcn_b + l * HID_,
        lng + l * HID_, lnb + l * HID_, hA, hB);
  }
  // cross attention layers (bf16 MFMA)
  for (int l = 0; l < 3; ++l) {
    const float* wq = cq + (size_t)l * HID_ * HID_;
    const float* wk = ck + (size_t)l * HID_ * HID_;
    const float* wv = cv + (size_t)l * HID_ * HID_;
    const float* wo = co + (size_t)l * HID_ * HID_;
    gemm128_bf16_k<0><<<dim3(128, 2), 256, 0, stream>>>(
        hA, hB, wq, SCALE_ATT * LOG2E, (ushort*)QA, (ushort*)QB);
    gemm128_bf16_k<0><<<dim3(128, 2), 256, 0, stream>>>(
        hA, hB, wk, 1.f, (ushort*)KAb, (ushort*)KBb);
    gemm128_bf16_k<1><<<dim3(128, 2), 256, 0, stream>>>(
        hA, hB, wv, 1.f, (ushort*)VAb, (ushort*)VBb);
    attn_mfma_k<<<dim3(64, 4, 2), 256, 0, stream>>>(
        (ushort*)QA, (ushort*)KAb, (ushort*)VAb, (ushort*)QB, (ushort*)KBb,
        (ushort*)VBb, tA, tB);
    gemm128_k<true, false, true><<<dim3(128, 2), 256, 0, stream>>>(
        tA, tB, wo, cob + l * HID_, hA, hB, aA, aB);
    float* t;
    t = hA; hA = aA; aA = t;
    t = hB; hB = aB; aB = t;
  }
  // post-LN + projection
  ln_k<<<dim3(1024, 2), 256, 0, stream>>>(hA, hB, plg, plb);
  gemm128_k<true, false, false><<<dim3(128, 2), 256, 0, stream>>>(
      hA, hB, pw, pb, nullptr, nullptr, Ap, Bp);
  // bf16 copies for the logits MFMA
  castf2b_k<<<256, 256, 0, stream>>>(Ap, Bp, Apb, Bpb);
  // logits + E = exp(L) (fp16), then null column
  gemm_nt_mfma_k<<<dim3(32, 32), 256, 0, stream>>>(Apb, Bpb, Lout, Eh);
  null_col_k<<<NN, 64, 0, stream>>>(Ap, nullv, Lout, Eh);
  // sinkhorn: u/v matvec iterations on fp16 E
  sink_init_k<<<17, 256, 0, stream>>>(t0);
  float* tcur = t0; float* tnext = t1;
  for (int it = 0; it < 20; ++it) {
    sink_rowm_k<<<256, 256, 0, stream>>>(Eh, tcur, tnext, uvec);
    sink_colm_k<<<dim3(9, 64), 256, 0, stream>>>(Eh, uvec, tnext);
    float* tt = tcur; tcur = tnext; tnext = tt;
  }
  sink_finalE_k<<<NN, 256, 0, stream>>>(Eh, uvec, tcur, Pout);
  // correspondence head
  gemm128_k<true, true, false><<<dim3(128, 2), 256, 0, stream>>>(
      Ap, Bp, w1, b1, nullptr, nullptr, tA, tB);
  gemm128_k<true, false, false><<<dim3(128, 2), 256, 0, stream>>>(
      tA, tB, w2, b2, nullptr, nullptr, zA, zB);
}